// Round 4
// baseline (14082.057 us; speedup 1.0000x reference)
//
#include <hip/hip_runtime.h>

#define NN 100000

__device__ __forceinline__ float bf2f(unsigned short u) {
    union { unsigned int ui; float f; } c;
    c.ui = ((unsigned int)u) << 16;
    return c.f;
}

__device__ __forceinline__ unsigned short f2bf(float f) {
    union { float ff; unsigned int ui; } c;
    c.ff = f;
    unsigned int u = c.ui;
    u += 0x7FFFu + ((u >> 16) & 1u);   // round-to-nearest-even
    return (unsigned short)(u >> 16);
}

__global__ void MultiTaskGCN_37623913513359_kernel() {}

// flags[0]: edge index format, 1 = int64, 0 = int32
// flags[1]: float dtype, 1 = bf16-backed, 0 = fp32-backed
__global__ void probe_fmt(const int* ei, const unsigned short* x, int* flags) {
    if (blockIdx.x != 0 || threadIdx.x != 0) return;
    int any = 0;
    for (int i = 0; i < 64; ++i) any |= ei[2 * i + 1];
    flags[0] = (any == 0) ? 1 : 0;
    // dtype probe: low half-words of fp32 data are mantissa garbage (huge
    // exponents appear with ~25% per sample); genuine bf16 N(0,1) stays small.
    int bf = 1;
    for (int i = 0; i < 512; ++i) {
        float v = bf2f(x[2 * i]);
        float av = v < 0.0f ? -v : v;
        if (!(v == v) || av > 1.0e6f) { bf = 0; break; }
    }
    flags[1] = bf;
}

__device__ __forceinline__ int edge_src(const int* ei, int is64, int e) {
    if (is64) return ei[2 * e];
    return ei[e];
}
__device__ __forceinline__ int edge_dst(const int* ei, int is64, int e, int E) {
    if (is64) return ei[2 * (E + e)];
    return ei[E + e];
}

__device__ __forceinline__ float load_f(const void* p, int dt, size_t i) {
    if (dt) return bf2f(((const unsigned short*)p)[i]);
    return ((const float*)p)[i];
}

__global__ __launch_bounds__(256) void count_deg(const int* ei, const int* flags,
                                                 float* deg, int E) {
    int t = blockIdx.x * 256 + threadIdx.x;
    if (t >= E) return;
    int is64 = flags[0];
    int s = edge_src(ei, is64, t);
    int d = edge_dst(ei, is64, t, E);
    if (((unsigned)s) >= NN || ((unsigned)d) >= NN) return;
    atomicAdd(&deg[d], 1.0f);
}

__global__ __launch_bounds__(256) void make_dinv(float* deg) {
    int i = blockIdx.x * 256 + threadIdx.x;
    if (i < NN) deg[i] = rsqrtf(deg[i] + 1.0f);   // +1 self loop
}

// pack [Wc | Wk | Wd | 0] into Wcat[256][64] fp32
__global__ __launch_bounds__(256) void pack_wcat(const void* Wc, const void* Wk,
                                                 const void* Wd, const int* flags,
                                                 float* Wcat) {
    int t = blockIdx.x * 256 + threadIdx.x;
    if (t >= 256 * 64) return;
    int dt = flags[1];
    int k = t >> 6;
    int n = t & 63;
    float v = 0.0f;
    if (n < 40) v = load_f(Wc, dt, (size_t)k * 40 + n);
    else if (n < 56) v = load_f(Wk, dt, (size_t)k * 16 + (n - 40));
    else if (n == 56) v = load_f(Wd, dt, k);
    Wcat[t] = v;
}

// O[M,N](bf16) = X[M,K] @ W[K,N]; X/W dtype via mode: 0=follow flag, 1=fp32, 2=bf16
__global__ __launch_bounds__(256) void gemm_any(const void* X, const void* W,
                                                unsigned short* O,
                                                int M, int N, int K,
                                                const int* flags,
                                                int xmode, int wmode) {
    __shared__ float Xs[64][17];
    __shared__ float Ws[16][65];

    int df = flags[1];
    int xdt = (xmode == 0) ? df : (xmode - 1);
    int wdt = (wmode == 0) ? df : (wmode - 1);

    int tid = threadIdx.x;
    int tx = tid & 15;
    int ty = tid >> 4;
    int m0 = blockIdx.x * 64;
    int n0 = blockIdx.y * 64;

    float acc[4][4];
    for (int i = 0; i < 4; ++i)
        for (int j = 0; j < 4; ++j)
            acc[i][j] = 0.0f;

    for (int k0 = 0; k0 < K; k0 += 16) {
        for (int i = 0; i < 4; ++i) {
            int idx = tid + 256 * i;          // 0..1023
            int r = idx >> 4, c = idx & 15;   // X tile 64x16
            int gr = m0 + r;
            if (gr >= M) gr = M - 1;
            Xs[r][c] = load_f(X, xdt, (size_t)gr * K + k0 + c);
            int r2 = idx >> 6, c2 = idx & 63; // W tile 16x64
            Ws[r2][c2] = load_f(W, wdt, (size_t)(k0 + r2) * N + n0 + c2);
        }
        __syncthreads();
#pragma unroll
        for (int kk = 0; kk < 16; ++kk) {
            float a0 = Xs[ty * 4 + 0][kk];
            float a1 = Xs[ty * 4 + 1][kk];
            float a2 = Xs[ty * 4 + 2][kk];
            float a3 = Xs[ty * 4 + 3][kk];
            float b0 = Ws[kk][tx * 4 + 0];
            float b1 = Ws[kk][tx * 4 + 1];
            float b2 = Ws[kk][tx * 4 + 2];
            float b3 = Ws[kk][tx * 4 + 3];
            acc[0][0] += a0 * b0; acc[0][1] += a0 * b1; acc[0][2] += a0 * b2; acc[0][3] += a0 * b3;
            acc[1][0] += a1 * b0; acc[1][1] += a1 * b1; acc[1][2] += a1 * b2; acc[1][3] += a1 * b3;
            acc[2][0] += a2 * b0; acc[2][1] += a2 * b1; acc[2][2] += a2 * b2; acc[2][3] += a2 * b3;
            acc[3][0] += a3 * b0; acc[3][1] += a3 * b1; acc[3][2] += a3 * b2; acc[3][3] += a3 * b3;
        }
        __syncthreads();
    }

    for (int i = 0; i < 4; ++i) {
        int gr = m0 + ty * 4 + i;
        if (gr < M) {
            for (int j = 0; j < 4; ++j) {
                O[(size_t)gr * N + n0 + tx * 4 + j] = f2bf(acc[i][j]);
            }
        }
    }
}

// edge scatter over a column chunk; cols/4 threads per edge, 4 cols each
__global__ __launch_bounds__(256) void scatter_cols(const int* ei, const int* flags,
                                                    const float* dinv,
                                                    const unsigned short* Xb, int ldxb,
                                                    int c0, float* S, int cols,
                                                    int lg_tpe, int E) {
    long long t = (long long)blockIdx.x * 256 + threadIdx.x;
    int e = (int)(t >> lg_tpe);
    if (e >= E) return;
    int l = ((int)t) & ((1 << lg_tpe) - 1);
    int is64 = flags[0];
    int s = edge_src(ei, is64, e);
    int d = edge_dst(ei, is64, e, E);
    if (((unsigned)s) >= NN || ((unsigned)d) >= NN) return;
    float w = dinv[s] * dinv[d];
    const unsigned short* xp = Xb + (size_t)s * ldxb + c0 + l * 4;
    float* sp = S + (size_t)d * cols + l * 4;
    atomicAdd(sp + 0, w * bf2f(xp[0]));
    atomicAdd(sp + 1, w * bf2f(xp[1]));
    atomicAdd(sp + 2, w * bf2f(xp[2]));
    atomicAdd(sp + 3, w * bf2f(xp[3]));
}

// h = relu(self-loop + aggregated + bias), in place over xw (bf16)
__global__ __launch_bounds__(256) void finalize1_chunk(unsigned short* xwb,
                                                       const float* S,
                                                       const void* b1,
                                                       const float* dinv,
                                                       const int* flags,
                                                       int c0, int cols, int csh) {
    long long t = (long long)blockIdx.x * 256 + threadIdx.x;
    if (t >= (long long)NN * cols) return;
    int dt = flags[1];
    int i = (int)(t >> csh);
    int f = ((int)t) & (cols - 1);
    int col = c0 + f;
    float di = dinv[i];
    size_t xi = (size_t)i * 256 + col;
    float v = di * di * bf2f(xwb[xi]) + S[t] + load_f(b1, dt, col);
    if (v < 0.0f) v = 0.0f;
    xwb[xi] = f2bf(v);
}

__global__ __launch_bounds__(256) void finalize2(const unsigned short* hw2b,
                                                 const float* S2,
                                                 const void* bc,
                                                 const void* bk,
                                                 const void* bd,
                                                 const float* dinv,
                                                 const int* flags,
                                                 void* outv) {
    int t = blockIdx.x * 256 + threadIdx.x;   // < NN*64
    int i = t >> 6;
    int f = t & 63;
    if (i >= NN) return;
    if (f >= 57) return;
    int dt = flags[1];
    float di = dinv[i];
    float v = di * di * bf2f(hw2b[t]) + S2[t];
    size_t o;
    if (f < 40) {
        v += load_f(bc, dt, f);
        o = (size_t)i * 40 + f;
    } else if (f < 56) {
        v += load_f(bk, dt, f - 40);
        o = (size_t)NN * 40 + (size_t)i * 16 + (f - 40);
    } else {
        v += load_f(bd, dt, 0);
        o = (size_t)NN * 56 + i;
    }
    if (dt) ((unsigned short*)outv)[o] = f2bf(v);
    else ((float*)outv)[o] = v;
}

extern "C" void kernel_launch(void* const* d_in, const int* in_sizes, int n_in,
                              void* d_out, int out_size, void* d_ws, size_t ws_size,
                              hipStream_t stream) {
    const void* x  = d_in[0];
    const int* ei  = (const int*)d_in[1];
    const void* W1 = d_in[2];
    const void* b1 = d_in[3];
    const void* Wc = d_in[4];
    const void* bc = d_in[5];
    const void* Wk = d_in[6];
    const void* bk = d_in[7];
    const void* Wd = d_in[8];
    const void* bd = d_in[9];

    int E = in_sizes[1] / 2;

    hipError_t herr = hipSuccess;
    hipError_t e;

    // fixed workspace layout (offsets 256B-aligned)
    char* ws = (char*)d_ws;
    size_t off = 0;
    float* dinv = (float*)(ws + off);                   off += 400128;      // NN*4
    int* flags = (int*)(ws + off);                      off += 256;
    float* Wcat = (float*)(ws + off);                   off += 65536;       // 256*64*4
    unsigned short* xwb  = (unsigned short*)(ws + off); off += (size_t)NN * 256 * 2;
    unsigned short* hw2b = (unsigned short*)(ws + off); off += (size_t)NN * 64 * 2;
    float* S2 = (float*)(ws + off);                     off += (size_t)NN * 64 * 4;
    float* S1 = (float*)(ws + off);

    size_t rem = (ws_size > off) ? (ws_size - off) : 0;
    int cols = 256;
    while (cols > 4 && (size_t)NN * cols * 4 > rem) cols /= 2;
    int ws_bad = ((size_t)NN * cols * 4 > rem) ? 1 : 0;

    int lg_tpe = 0;
    while ((1 << lg_tpe) < cols / 4) ++lg_tpe;
    int csh = 0;
    while ((1 << csh) < cols) ++csh;

    if (!ws_bad) {
        e = hipMemsetAsync(dinv, 0, (size_t)NN * 4, stream);
        if (herr == hipSuccess && e != hipSuccess) herr = e;
        e = hipMemsetAsync(S2, 0, (size_t)NN * 64 * 4, stream);
        if (herr == hipSuccess && e != hipSuccess) herr = e;

        probe_fmt<<<1, 64, 0, stream>>>(ei, (const unsigned short*)x, flags);
        pack_wcat<<<64, 256, 0, stream>>>(Wc, Wk, Wd, flags, Wcat);
        count_deg<<<(E + 255) / 256, 256, 0, stream>>>(ei, flags, dinv, E);
        make_dinv<<<(NN + 255) / 256, 256, 0, stream>>>(dinv);

        // layer 1: xw = x @ W1   (M=100000, K=512, N=256), W1 dtype follows flag
        {
            dim3 grid((NN + 63) / 64, 4);
            gemm_any<<<grid, 256, 0, stream>>>(x, W1, xwb, NN, 256, 512, flags, 0, 0);
        }

        for (int c0 = 0; c0 < 256; c0 += cols) {
            e = hipMemsetAsync(S1, 0, (size_t)NN * cols * 4, stream);
            if (herr == hipSuccess && e != hipSuccess) herr = e;
            long long nthr = (long long)E * (cols / 4);
            int blocks = (int)((nthr + 255) / 256);
            scatter_cols<<<blocks, 256, 0, stream>>>(ei, flags, dinv, xwb, 256, c0,
                                                     S1, cols, lg_tpe, E);
            long long nf = (long long)NN * cols;
            finalize1_chunk<<<(int)((nf + 255) / 256), 256, 0, stream>>>(
                xwb, S1, b1, dinv, flags, c0, cols, csh);
        }

        // layer 2: hw2 = h @ Wcat  (M=100000, K=256, N=64); X bf16, W fp32
        {
            dim3 grid((NN + 63) / 64, 1);
            gemm_any<<<grid, 256, 0, stream>>>(xwb, Wcat, hw2b, NN, 64, 256, flags, 2, 1);
        }
        {
            long long nthr = (long long)E * 16;
            int blocks = (int)((nthr + 255) / 256);
            scatter_cols<<<blocks, 256, 0, stream>>>(ei, flags, dinv, hw2b, 64, 0,
                                                     S2, 64, 4, E);
        }
        finalize2<<<NN * 64 / 256, 256, 0, stream>>>(hw2b, S2, bc, bk, bd, dinv,
                                                     flags, d_out);
    }

    e = hipGetLastError();
    if (herr == hipSuccess && e != hipSuccess) herr = e;

    // diagnostic stamp (decodable via absmax) — only on failure
    if (herr != hipSuccess) {
        (void)hipMemsetAsync(d_out, 0x41 + ((int)herr & 7), 128, stream);
    }
    if (ws_bad) {
        (void)hipMemsetAsync(d_out, 0x58, 128, stream);
    }
}

// Round 5
// 2050.583 us; speedup vs baseline: 6.8673x; 6.8673x over previous
//
#include <hip/hip_runtime.h>

#define NN 100000

__device__ __forceinline__ float bf2f(unsigned short u) {
    union { unsigned int ui; float f; } c;
    c.ui = ((unsigned int)u) << 16;
    return c.f;
}

__device__ __forceinline__ unsigned short f2bf(float f) {
    union { float ff; unsigned int ui; } c;
    c.ff = f;
    unsigned int u = c.ui;
    u += 0x7FFFu + ((u >> 16) & 1u);   // round-to-nearest-even
    return (unsigned short)(u >> 16);
}

__global__ void MultiTaskGCN_37623913513359_kernel() {}

// flags[0]: edge index format, 1 = int64, 0 = int32
// flags[1]: float dtype, 1 = bf16-backed, 0 = fp32-backed
__global__ void probe_fmt(const int* ei, const unsigned short* x, int* flags) {
    if (blockIdx.x != 0 || threadIdx.x != 0) return;
    int any = 0;
    for (int i = 0; i < 64; ++i) any |= ei[2 * i + 1];
    flags[0] = (any == 0) ? 1 : 0;
    int bf = 1;
    for (int i = 0; i < 512; ++i) {
        float v = bf2f(x[2 * i]);
        float av = v < 0.0f ? -v : v;
        if (!(v == v) || av > 1.0e6f) { bf = 0; break; }
    }
    flags[1] = bf;
}

__device__ __forceinline__ int edge_src(const int* ei, int is64, int e) {
    if (is64) return ei[2 * e];
    return ei[e];
}
__device__ __forceinline__ int edge_dst(const int* ei, int is64, int e, int E) {
    if (is64) return ei[2 * (E + e)];
    return ei[E + e];
}

__device__ __forceinline__ float load_f(const void* p, int dt, size_t i) {
    if (dt) return bf2f(((const unsigned short*)p)[i]);
    return ((const float*)p)[i];
}

__global__ __launch_bounds__(256) void count_deg_i(const int* ei, const int* flags,
                                                   int* degi, int E) {
    int t = blockIdx.x * 256 + threadIdx.x;
    if (t >= E) return;
    int is64 = flags[0];
    int s = edge_src(ei, is64, t);
    int d = edge_dst(ei, is64, t, E);
    if (((unsigned)s) >= NN || ((unsigned)d) >= NN) return;
    atomicAdd(&degi[d], 1);
}

__global__ __launch_bounds__(256) void make_dinv(const int* degi, float* dinv) {
    int i = blockIdx.x * 256 + threadIdx.x;
    if (i < NN) dinv[i] = rsqrtf((float)degi[i] + 1.0f);   // +1 self loop
}

// single-block exclusive scan of degi -> rowptr (NN+1 entries)
__global__ __launch_bounds__(1024) void scan_rowptr(const int* degi, int* rowptr) {
    __shared__ int part[1024];
    int tid = threadIdx.x;
    const int chunk = (NN + 1023) / 1024;   // 98
    int base = tid * chunk;
    int s = 0;
    for (int j = 0; j < chunk; ++j) {
        int i = base + j;
        if (i < NN) s += degi[i];
    }
    part[tid] = s;
    __syncthreads();
    for (int off = 1; off < 1024; off <<= 1) {
        int v = (tid >= off) ? part[tid - off] : 0;
        __syncthreads();
        part[tid] += v;
        __syncthreads();
    }
    int run = (tid == 0) ? 0 : part[tid - 1];
    for (int j = 0; j < chunk; ++j) {
        int i = base + j;
        if (i < NN) {
            rowptr[i] = run;
            run += degi[i];
        }
    }
    if (tid == 1023) rowptr[NN] = part[1023];
}

// fill CSR: packed entry = (w_bits << 32) | src
__global__ __launch_bounds__(256) void fill_csr(const int* ei, const int* flags,
                                                const float* dinv, const int* rowptr,
                                                int* cursor, unsigned long long* csr,
                                                int E) {
    int t = blockIdx.x * 256 + threadIdx.x;
    if (t >= E) return;
    int is64 = flags[0];
    int s = edge_src(ei, is64, t);
    int d = edge_dst(ei, is64, t, E);
    if (((unsigned)s) >= NN || ((unsigned)d) >= NN) return;
    int pos = rowptr[d] + atomicAdd(&cursor[d], 1);
    float w = dinv[s] * dinv[d];
    union { float ff; unsigned int ui; } c;
    c.ff = w;
    csr[pos] = ((unsigned long long)c.ui << 32) | (unsigned int)s;
}

// pack [Wc | Wk | Wd | 0] into Wcat[256][64] fp32
__global__ __launch_bounds__(256) void pack_wcat(const void* Wc, const void* Wk,
                                                 const void* Wd, const int* flags,
                                                 float* Wcat) {
    int t = blockIdx.x * 256 + threadIdx.x;
    if (t >= 256 * 64) return;
    int dt = flags[1];
    int k = t >> 6;
    int n = t & 63;
    float v = 0.0f;
    if (n < 40) v = load_f(Wc, dt, (size_t)k * 40 + n);
    else if (n < 56) v = load_f(Wk, dt, (size_t)k * 16 + (n - 40));
    else if (n == 56) v = load_f(Wd, dt, k);
    Wcat[t] = v;
}

// O[M,N](bf16) = X[M,K] @ W[K,N]; dtype modes: 0=follow flag, 1=fp32, 2=bf16
__global__ __launch_bounds__(256) void gemm_any(const void* X, const void* W,
                                                unsigned short* O,
                                                int M, int N, int K,
                                                const int* flags,
                                                int xmode, int wmode) {
    __shared__ float Xs[64][17];
    __shared__ float Ws[16][65];

    int df = flags[1];
    int xdt = (xmode == 0) ? df : (xmode - 1);
    int wdt = (wmode == 0) ? df : (wmode - 1);

    int tid = threadIdx.x;
    int tx = tid & 15;
    int ty = tid >> 4;
    int m0 = blockIdx.x * 64;
    int n0 = blockIdx.y * 64;

    float acc[4][4];
    for (int i = 0; i < 4; ++i)
        for (int j = 0; j < 4; ++j)
            acc[i][j] = 0.0f;

    for (int k0 = 0; k0 < K; k0 += 16) {
        for (int i = 0; i < 4; ++i) {
            int idx = tid + 256 * i;
            int r = idx >> 4, c = idx & 15;
            int gr = m0 + r;
            if (gr >= M) gr = M - 1;
            Xs[r][c] = load_f(X, xdt, (size_t)gr * K + k0 + c);
            int r2 = idx >> 6, c2 = idx & 63;
            Ws[r2][c2] = load_f(W, wdt, (size_t)(k0 + r2) * N + n0 + c2);
        }
        __syncthreads();
#pragma unroll
        for (int kk = 0; kk < 16; ++kk) {
            float a0 = Xs[ty * 4 + 0][kk];
            float a1 = Xs[ty * 4 + 1][kk];
            float a2 = Xs[ty * 4 + 2][kk];
            float a3 = Xs[ty * 4 + 3][kk];
            float b0 = Ws[kk][tx * 4 + 0];
            float b1 = Ws[kk][tx * 4 + 1];
            float b2 = Ws[kk][tx * 4 + 2];
            float b3 = Ws[kk][tx * 4 + 3];
            acc[0][0] += a0 * b0; acc[0][1] += a0 * b1; acc[0][2] += a0 * b2; acc[0][3] += a0 * b3;
            acc[1][0] += a1 * b0; acc[1][1] += a1 * b1; acc[1][2] += a1 * b2; acc[1][3] += a1 * b3;
            acc[2][0] += a2 * b0; acc[2][1] += a2 * b1; acc[2][2] += a2 * b2; acc[2][3] += a2 * b3;
            acc[3][0] += a3 * b0; acc[3][1] += a3 * b1; acc[3][2] += a3 * b2; acc[3][3] += a3 * b3;
        }
        __syncthreads();
    }

    for (int i = 0; i < 4; ++i) {
        int gr = m0 + ty * 4 + i;
        if (gr < M) {
            for (int j = 0; j < 4; ++j) {
                O[(size_t)gr * N + n0 + tx * 4 + j] = f2bf(acc[i][j]);
            }
        }
    }
}

// layer-1 aggregation by pull + fused epilogue: one wave per destination node.
// lane owns 4 cols of 256; h = relu(dinv^2*xw[i] + sum_e w*xw[src] + b1)
__global__ __launch_bounds__(256) void gather_h(const int* rowptr,
                                                const unsigned long long* csr,
                                                const unsigned short* xwb,
                                                const void* b1,
                                                const float* dinv,
                                                const int* flags,
                                                unsigned short* hb) {
    int node = (blockIdx.x * 256 + threadIdx.x) >> 6;
    int lane = threadIdx.x & 63;
    if (node >= NN) return;
    int beg = rowptr[node], end = rowptr[node + 1];
    float a0 = 0.f, a1 = 0.f, a2 = 0.f, a3 = 0.f;
    for (int e = beg; e < end; ++e) {
        unsigned long long p = csr[e];
        int s = (int)(unsigned int)(p & 0xFFFFFFFFu);
        union { unsigned int ui; float ff; } c;
        c.ui = (unsigned int)(p >> 32);
        float w = c.ff;
        unsigned long long v = *(const unsigned long long*)(xwb + (size_t)s * 256 + lane * 4);
        a0 += w * bf2f((unsigned short)v);
        a1 += w * bf2f((unsigned short)(v >> 16));
        a2 += w * bf2f((unsigned short)(v >> 32));
        a3 += w * bf2f((unsigned short)(v >> 48));
    }
    int dt = flags[1];
    float di = dinv[node];
    float sl = di * di;
    size_t base = (size_t)node * 256 + lane * 4;
    unsigned long long v = *(const unsigned long long*)(xwb + base);
    float r0 = sl * bf2f((unsigned short)v)         + a0 + load_f(b1, dt, lane * 4 + 0);
    float r1 = sl * bf2f((unsigned short)(v >> 16)) + a1 + load_f(b1, dt, lane * 4 + 1);
    float r2 = sl * bf2f((unsigned short)(v >> 32)) + a2 + load_f(b1, dt, lane * 4 + 2);
    float r3 = sl * bf2f((unsigned short)(v >> 48)) + a3 + load_f(b1, dt, lane * 4 + 3);
    if (r0 < 0.f) r0 = 0.f;
    if (r1 < 0.f) r1 = 0.f;
    if (r2 < 0.f) r2 = 0.f;
    if (r3 < 0.f) r3 = 0.f;
    unsigned long long o = (unsigned long long)f2bf(r0)
                         | ((unsigned long long)f2bf(r1) << 16)
                         | ((unsigned long long)f2bf(r2) << 32)
                         | ((unsigned long long)f2bf(r3) << 48);
    *(unsigned long long*)(hb + base) = o;
}

// layer-2 aggregation by pull + fused head routing: one wave per node, lane = col
__global__ __launch_bounds__(256) void gather_out(const int* rowptr,
                                                  const unsigned long long* csr,
                                                  const unsigned short* hw2b,
                                                  const void* bc, const void* bk,
                                                  const void* bd,
                                                  const float* dinv,
                                                  const int* flags,
                                                  void* outv) {
    int node = (blockIdx.x * 256 + threadIdx.x) >> 6;
    int lane = threadIdx.x & 63;
    if (node >= NN) return;
    int beg = rowptr[node], end = rowptr[node + 1];
    float acc = 0.f;
    for (int e = beg; e < end; ++e) {
        unsigned long long p = csr[e];
        int s = (int)(unsigned int)(p & 0xFFFFFFFFu);
        union { unsigned int ui; float ff; } c;
        c.ui = (unsigned int)(p >> 32);
        acc += c.ff * bf2f(hw2b[(size_t)s * 64 + lane]);
    }
    if (lane >= 57) return;
    int dt = flags[1];
    float di = dinv[node];
    float v = di * di * bf2f(hw2b[(size_t)node * 64 + lane]) + acc;
    size_t o;
    if (lane < 40) {
        v += load_f(bc, dt, lane);
        o = (size_t)node * 40 + lane;
    } else if (lane < 56) {
        v += load_f(bk, dt, lane - 40);
        o = (size_t)NN * 40 + (size_t)node * 16 + (lane - 40);
    } else {
        v += load_f(bd, dt, 0);
        o = (size_t)NN * 56 + node;
    }
    if (dt) ((unsigned short*)outv)[o] = f2bf(v);
    else ((float*)outv)[o] = v;
}

extern "C" void kernel_launch(void* const* d_in, const int* in_sizes, int n_in,
                              void* d_out, int out_size, void* d_ws, size_t ws_size,
                              hipStream_t stream) {
    const void* x  = d_in[0];
    const int* ei  = (const int*)d_in[1];
    const void* W1 = d_in[2];
    const void* b1 = d_in[3];
    const void* Wc = d_in[4];
    const void* bc = d_in[5];
    const void* Wk = d_in[6];
    const void* bk = d_in[7];
    const void* Wd = d_in[8];
    const void* bd = d_in[9];

    int E = in_sizes[1] / 2;

    hipError_t herr = hipSuccess;
    hipError_t e;

    // workspace layout (256B-aligned offsets)
    char* ws = (char*)d_ws;
    size_t off = 0;
    int* flags = (int*)(ws + off);                      off += 256;
    int* degi = (int*)(ws + off);                       off += 400128;
    float* dinv = (float*)(ws + off);                   off += 400128;
    int* rowptr = (int*)(ws + off);                     off += 400384;   // NN+1
    int* cursor = (int*)(ws + off);                     off += 400128;
    float* Wcat = (float*)(ws + off);                   off += 65536;
    unsigned long long* csr = (unsigned long long*)(ws + off); off += (size_t)E * 8;
    unsigned short* xwb = (unsigned short*)(ws + off);  off += (size_t)NN * 256 * 2;
    unsigned short* hb = (unsigned short*)(ws + off);   off += (size_t)NN * 256 * 2;
    unsigned short* hw2b = (unsigned short*)(ws + off); off += (size_t)NN * 64 * 2;

    int ws_bad = (off > ws_size) ? 1 : 0;

    if (!ws_bad) {
        e = hipMemsetAsync(degi, 0, (size_t)NN * 4, stream);
        if (herr == hipSuccess && e != hipSuccess) herr = e;
        e = hipMemsetAsync(cursor, 0, (size_t)NN * 4, stream);
        if (herr == hipSuccess && e != hipSuccess) herr = e;

        probe_fmt<<<1, 64, 0, stream>>>(ei, (const unsigned short*)x, flags);
        pack_wcat<<<64, 256, 0, stream>>>(Wc, Wk, Wd, flags, Wcat);
        count_deg_i<<<(E + 255) / 256, 256, 0, stream>>>(ei, flags, degi, E);
        make_dinv<<<(NN + 255) / 256, 256, 0, stream>>>(degi, dinv);
        scan_rowptr<<<1, 1024, 0, stream>>>(degi, rowptr);
        fill_csr<<<(E + 255) / 256, 256, 0, stream>>>(ei, flags, dinv, rowptr,
                                                      cursor, csr, E);

        // layer 1: xw = x @ W1   (M=100000, K=512, N=256)
        {
            dim3 grid((NN + 63) / 64, 4);
            gemm_any<<<grid, 256, 0, stream>>>(x, W1, xwb, NN, 256, 512, flags, 0, 0);
        }
        gather_h<<<(NN + 3) / 4, 256, 0, stream>>>(rowptr, csr, xwb, b1, dinv,
                                                   flags, hb);

        // layer 2: hw2 = h @ Wcat   (M=100000, K=256, N=64)
        {
            dim3 grid((NN + 63) / 64, 1);
            gemm_any<<<grid, 256, 0, stream>>>(hb, Wcat, hw2b, NN, 64, 256, flags, 2, 1);
        }
        gather_out<<<(NN + 3) / 4, 256, 0, stream>>>(rowptr, csr, hw2b, bc, bk, bd,
                                                     dinv, flags, d_out);
    }

    e = hipGetLastError();
    if (herr == hipSuccess && e != hipSuccess) herr = e;

    if (herr != hipSuccess) {
        (void)hipMemsetAsync(d_out, 0x41 + ((int)herr & 7), 128, stream);
    }
    if (ws_bad) {
        (void)hipMemsetAsync(d_out, 0x58, 128, stream);
    }
}